// Round 1
// baseline (1579.746 us; speedup 1.0000x reference)
//
#include <hip/hip_runtime.h>

// MHSA with relative position bias (Swin window attention), MI355X gfx950.
// B=2048 windows, N=49 tokens, C=1024, 16 heads x 64. All math in fp16 MFMA
// with fp32 accumulation; error budget ~3e-3 vs threshold 2.9e-2.
//
// Pipeline: cvt(x,w) -> GEMM1 qkv[fp16] -> attn (per b,h wave) -> GEMM2 -> out fp32
// Workspace: ~989 MB.

typedef _Float16 f16;
typedef _Float16 f16x8 __attribute__((ext_vector_type(8)));
typedef _Float16 f16x4 __attribute__((ext_vector_type(4)));
typedef float f32x4 __attribute__((ext_vector_type(4)));

#define G1P(p) ((const __attribute__((address_space(1))) unsigned int*)(p))
#define L3P(p) ((__attribute__((address_space(3))) unsigned int*)(p))

static const int MTOT = 100352;          // 2048*49, = 784*128 exactly
static const size_t MROW_MAX = 100351;   // clamp for padded rows 49..63

// ---------------- fp32 -> fp16 convert (vec4) ----------------
__global__ void cvt_kernel(const float* __restrict__ in, f16* __restrict__ out, int n4) {
  int i = blockIdx.x * blockDim.x + threadIdx.x;
  int stride = gridDim.x * blockDim.x;
  const float4* in4 = (const float4*)in;
  f16x4* out4 = (f16x4*)out;
  for (; i < n4; i += stride) {
    float4 v = in4[i];
    f16x4 o = { (f16)v.x, (f16)v.y, (f16)v.z, (f16)v.w };
    out4[i] = o;
  }
}

// ---------------- bias table: bias_all[h][64][64], mask folded in ----------------
// bias[h,n,m] = rpb[h, i_m - i_n + 6, j_m - j_n + 6] (derived from the flipped
// relative_position_index); -1e30 for padded n/m >= 49 (softmax mask).
__global__ void bias_kernel(const float* __restrict__ rpb, float* __restrict__ bias_all) {
  int h = blockIdx.x;
  for (int e = threadIdx.x; e < 4096; e += blockDim.x) {
    int n = e >> 6, m = e & 63;
    float v = -1e30f;
    if (n < 49 && m < 49) {
      int in_ = n / 7, jn = n % 7, im = m / 7, jm = m % 7;
      v = rpb[h * 169 + (im - in_ + 6) * 13 + (jm - jn + 6)];
    }
    bias_all[h * 4096 + e] = v;
  }
}

// ---------------- GEMM: C[M,N] = A[M,K] @ B[N,K]^T + bias ----------------
// m97-structure: 128x128 tile, BK=64, 4 waves (2x2), 16x16x32 f16 MFMA.
// LDS staged via global_load_lds width-16 with pre-swizzled SOURCE address
// (linear LDS dest; logical byte = phys byte ^ ((row&7)<<4)) so fragment
// ds_read_b128 is 2-way (free) instead of 16-way conflicted.
template <typename OutT>
__global__ __launch_bounds__(256, 2)
void gemm_tn(const f16* __restrict__ A, const f16* __restrict__ B,
             const float* __restrict__ bias, OutT* __restrict__ C,
             int N, int K) {
  __shared__ char lds[32768];  // A tile [0,16K), B tile [16K,32K)
  const int m0 = blockIdx.x * 128;
  const int n0 = blockIdx.y * 128;
  const int tid = threadIdx.x;
  const int wv = tid >> 6, ln = tid & 63;
  const int l15 = ln & 15, lhi = ln >> 4;
  const int wm = wv >> 1, wn = wv & 1;
  const int rA = ln >> 3, lc = ln & 7;

  f32x4 acc[4][4];
#pragma unroll
  for (int i = 0; i < 4; ++i)
#pragma unroll
    for (int j = 0; j < 4; ++j) acc[i][j] = (f32x4){0.f, 0.f, 0.f, 0.f};

  for (int k0 = 0; k0 < K; k0 += 64) {
    if (k0) __syncthreads();
#pragma unroll
    for (int c = 0; c < 4; ++c) {   // A tile: 16KB, 16 slots of 1KB
      int slot = wv * 4 + c;
      int r = slot * 8 + rA;        // tile row 0..127
      int ce = (lc ^ (r & 7)) << 3; // swizzled source element col
      const f16* g = A + (size_t)(m0 + r) * K + (k0 + ce);
      __builtin_amdgcn_global_load_lds(G1P(g), L3P(lds + slot * 1024), 16, 0, 0);
    }
#pragma unroll
    for (int c = 0; c < 4; ++c) {   // B tile
      int slot = wv * 4 + c;
      int r = slot * 8 + rA;
      int ce = (lc ^ (r & 7)) << 3;
      const f16* g = B + (size_t)(n0 + r) * K + (k0 + ce);
      __builtin_amdgcn_global_load_lds(G1P(g), L3P(lds + 16384 + slot * 1024), 16, 0, 0);
    }
    __syncthreads();
#pragma unroll
    for (int kk = 0; kk < 2; ++kk) {
      f16x8 af[4], bf[4];
#pragma unroll
      for (int t = 0; t < 4; ++t) {
        int row = wm * 64 + t * 16 + l15;
        int pb = (kk * 64 + lhi * 16) ^ ((row & 7) << 4);
        af[t] = *(const f16x8*)(lds + row * 128 + pb);
        int rowb = wn * 64 + t * 16 + l15;
        int pbb = (kk * 64 + lhi * 16) ^ ((rowb & 7) << 4);
        bf[t] = *(const f16x8*)(lds + 16384 + rowb * 128 + pbb);
      }
#pragma unroll
      for (int i = 0; i < 4; ++i)
#pragma unroll
        for (int j = 0; j < 4; ++j)
          acc[i][j] = __builtin_amdgcn_mfma_f32_16x16x32_f16(af[i], bf[j], acc[i][j], 0, 0, 0);
    }
  }
  // epilogue: C row = (lane>>4)*4+reg, col = lane&15 (m89-verified layout)
#pragma unroll
  for (int i = 0; i < 4; ++i)
#pragma unroll
    for (int j = 0; j < 4; ++j)
#pragma unroll
      for (int r = 0; r < 4; ++r) {
        int gr = m0 + wm * 64 + i * 16 + lhi * 4 + r;
        int gc = n0 + wn * 64 + j * 16 + l15;
        float v = acc[i][j][r] + bias[gc];
        C[(size_t)gr * N + gc] = (OutT)v;
      }
}

// ---------------- attention: one wave per (window, head) ----------------
__global__ __launch_bounds__(64)
void attn_kernel(const f16* __restrict__ qkv,       // [MTOT][3072] q|k|v, head-major 64
                 const float* __restrict__ bias_all, // [16][64][64]
                 f16* __restrict__ out) {             // [MTOT][1024]
  __shared__ char lds[24576];  // K:[0,8K)  Vt:[8K,16K)  P:[16K,24K)
  const int bh = blockIdx.x;
  const int b = bh >> 4, h = bh & 15;
  const int ln = threadIdx.x;
  const int l15 = ln & 15, lhi = ln >> 4;
  const size_t base = (size_t)b * 49;

  // Q fragments from global (A-operand: row = lane&15, k = (lane>>4)*8..)
  f16x8 qf[4][2];
#pragma unroll
  for (int t = 0; t < 4; ++t) {
    size_t row = base + t * 16 + l15;
    if (row > MROW_MAX) row = MROW_MAX;  // padded rows: finite garbage, discarded
    const f16* qp = qkv + row * 3072 + h * 64 + lhi * 8;
    qf[t][0] = *(const f16x8*)(qp);
    qf[t][1] = *(const f16x8*)(qp + 32);
  }
  // K tile -> LDS (swizzled source, linear dest)
  {
    int rA = ln >> 3, lc = ln & 7;
#pragma unroll
    for (int c = 0; c < 8; ++c) {
      int r = c * 8 + rA;
      int ce = (lc ^ (r & 7)) << 3;
      size_t row = base + r;
      if (row > MROW_MAX) row = MROW_MAX;
      const f16* g = qkv + row * 3072 + 1024 + h * 64 + ce;
      __builtin_amdgcn_global_load_lds(G1P(g), L3P(lds + c * 1024), 16, 0, 0);
    }
  }
  // V row -> regs -> transposed LDS Vt[d][m] (so PV B-frag reads are contiguous)
  {
    size_t row = base + ln;
    if (row > MROW_MAX) row = MROW_MAX;
    const f16* vp = qkv + row * 3072 + 2048 + h * 64;
    f16x8 vr[8];
#pragma unroll
    for (int j = 0; j < 8; ++j) vr[j] = *(const f16x8*)(vp + j * 8);
#pragma unroll
    for (int d = 0; d < 64; ++d)
      *(f16*)(lds + 8192 + d * 128 + ((ln * 2) ^ ((d & 7) << 4))) = vr[d >> 3][d & 7];
  }
  __syncthreads();

  // S = Q @ K^T  (64x64 padded; cols m>=49 masked later via bias table)
  f32x4 acc[4][4];
#pragma unroll
  for (int i = 0; i < 4; ++i)
#pragma unroll
    for (int j = 0; j < 4; ++j) acc[i][j] = (f32x4){0.f, 0.f, 0.f, 0.f};
#pragma unroll
  for (int kk = 0; kk < 2; ++kk) {
    f16x8 bf[4];
#pragma unroll
    for (int t = 0; t < 4; ++t) {
      int mr = t * 16 + l15;
      int pb = (kk * 64 + lhi * 16) ^ ((mr & 7) << 4);
      bf[t] = *(const f16x8*)(lds + mr * 128 + pb);
    }
#pragma unroll
    for (int i = 0; i < 4; ++i)
#pragma unroll
      for (int j = 0; j < 4; ++j)
        acc[i][j] = __builtin_amdgcn_mfma_f32_16x16x32_f16(qf[i][kk], bf[j], acc[i][j], 0, 0, 0);
  }

  // softmax per row (scale 0.125, + bias; reduce across 16-lane col group)
  const float* bb = bias_all + h * 4096;
#pragma unroll
  for (int i = 0; i < 4; ++i) {
#pragma unroll
    for (int r = 0; r < 4; ++r) {
      int n = i * 16 + lhi * 4 + r;
      float lv[4];
#pragma unroll
      for (int j = 0; j < 4; ++j)
        lv[j] = acc[i][j][r] * 0.125f + bb[n * 64 + j * 16 + l15];
      float Mx = fmaxf(fmaxf(lv[0], lv[1]), fmaxf(lv[2], lv[3]));
#pragma unroll
      for (int off = 1; off < 16; off <<= 1) Mx = fmaxf(Mx, __shfl_xor(Mx, off));
      float s = 0.f;
#pragma unroll
      for (int j = 0; j < 4; ++j) { lv[j] = __expf(lv[j] - Mx); s += lv[j]; }
#pragma unroll
      for (int off = 1; off < 16; off <<= 1) s += __shfl_xor(s, off);
      float inv = 1.f / s;
#pragma unroll
      for (int j = 0; j < 4; ++j) {
        int m = j * 16 + l15;
        *(f16*)(lds + 16384 + n * 128 + ((m * 2) ^ ((n & 7) << 4))) = (f16)(lv[j] * inv);
      }
    }
  }
  __syncthreads();

  // O = P @ V  (A = P rows n, B-frag from Vt[d][m])
  f32x4 o[4][4];
#pragma unroll
  for (int i = 0; i < 4; ++i)
#pragma unroll
    for (int j = 0; j < 4; ++j) o[i][j] = (f32x4){0.f, 0.f, 0.f, 0.f};
#pragma unroll
  for (int kk = 0; kk < 2; ++kk) {
    f16x8 af[4], bf[4];
#pragma unroll
    for (int t = 0; t < 4; ++t) {
      int nr = t * 16 + l15;
      int pb = (kk * 64 + lhi * 16) ^ ((nr & 7) << 4);
      af[t] = *(const f16x8*)(lds + 16384 + nr * 128 + pb);
      bf[t] = *(const f16x8*)(lds + 8192 + nr * 128 + pb);  // d-row == same index expr
    }
#pragma unroll
    for (int i = 0; i < 4; ++i)
#pragma unroll
      for (int j = 0; j < 4; ++j)
        o[i][j] = __builtin_amdgcn_mfma_f32_16x16x32_f16(af[i], bf[j], o[i][j], 0, 0, 0);
  }
  // store rows n<49, fp16 [MTOT][1024]
#pragma unroll
  for (int i = 0; i < 4; ++i)
#pragma unroll
    for (int j = 0; j < 4; ++j)
#pragma unroll
      for (int r = 0; r < 4; ++r) {
        int n = i * 16 + lhi * 4 + r;
        if (n < 49)
          out[(base + n) * 1024 + h * 64 + j * 16 + l15] = (f16)o[i][j][r];
      }
}

extern "C" void kernel_launch(void* const* d_in, const int* in_sizes, int n_in,
                              void* d_out, int out_size, void* d_ws, size_t ws_size,
                              hipStream_t stream) {
  const float* x      = (const float*)d_in[0];  // [100352][1024]
  const float* qkv_w  = (const float*)d_in[1];  // [3072][1024]
  const float* qkv_b  = (const float*)d_in[2];  // [3072]
  const float* rpb    = (const float*)d_in[3];  // [16][13][13]
  const float* proj_w = (const float*)d_in[4];  // [1024][1024]
  const float* proj_b = (const float*)d_in[5];  // [1024]
  float* out = (float*)d_out;

  char* ws = (char*)d_ws;
  // layout (bytes): all 256B-aligned; total ~989 MB
  f16*   x16      = (f16*)(ws);                              // 205,520,896
  f16*   wq16     = (f16*)(ws + 205520896);                  //   6,291,456
  f16*   wp16     = (f16*)(ws + 211812352);                  //   2,097,152
  f16*   qkv16    = (f16*)(ws + 213909504);                  // 616,562,688
  f16*   attn16   = (f16*)(ws + 830472192);                  // 205,520,896
  float* bias_all = (float*)(ws + 1035993088);               //     262,144

  cvt_kernel<<<2048, 256, 0, stream>>>(x, x16, 102760448 / 4);
  cvt_kernel<<<1024, 256, 0, stream>>>(qkv_w, wq16, 3145728 / 4);
  cvt_kernel<<<512, 256, 0, stream>>>(proj_w, wp16, 1048576 / 4);
  bias_kernel<<<16, 64, 0, stream>>>(rpb, bias_all);

  // qkv = x @ qkv_w^T + qkv_b   [100352][3072] fp16
  gemm_tn<f16><<<dim3(784, 24), 256, 0, stream>>>(x16, wq16, qkv_b, qkv16, 3072, 1024);
  // attention per (window, head)
  attn_kernel<<<2048 * 16, 64, 0, stream>>>(qkv16, bias_all, attn16);
  // out = attn @ proj_w^T + proj_b   [100352][1024] fp32
  gemm_tn<float><<<dim3(784, 8), 256, 0, stream>>>(attn16, wp16, proj_b, out, 1024, 1024);
}

// Round 2
// 1348.433 us; speedup vs baseline: 1.1715x; 1.1715x over previous
//
#include <hip/hip_runtime.h>

// MHSA with relative position bias (Swin window attention), MI355X gfx950.
// B=2048 windows, N=49 tokens, C=1024, 16 heads x 64. fp16 MFMA, fp32 accum.
// Round 2: GEMMs ported to the 256x256 8-phase schedule (T2+T3+T4+T5):
//   BK=64 split into two K-half panels [kk][256][32] (16KB halves, LDS-contiguous),
//   2-deep LDS double buffer (128 KiB), 1 half-tile global_load_lds stage per phase,
//   counted vmcnt(4) at phases 4/8 only, setprio around MFMA clusters,
//   swizzle folded into global source (lane-const chunk XOR), XCD-chunked grid.

typedef _Float16 f16;
typedef _Float16 f16x8 __attribute__((ext_vector_type(8)));
typedef _Float16 f16x4 __attribute__((ext_vector_type(4)));
typedef float f32x4 __attribute__((ext_vector_type(4)));

#define G1P(p) ((const __attribute__((address_space(1))) unsigned int*)(p))
#define L3P(p) ((__attribute__((address_space(3))) unsigned int*)(p))

static const size_t MROW_MAX = 100351;   // clamp for padded rows 49..63 (attn)

// ---------------- fp32 -> fp16 convert (vec4) ----------------
__global__ void cvt_kernel(const float* __restrict__ in, f16* __restrict__ out, int n4) {
  int i = blockIdx.x * blockDim.x + threadIdx.x;
  int stride = gridDim.x * blockDim.x;
  const float4* in4 = (const float4*)in;
  f16x4* out4 = (f16x4*)out;
  for (; i < n4; i += stride) {
    float4 v = in4[i];
    f16x4 o = { (f16)v.x, (f16)v.y, (f16)v.z, (f16)v.w };
    out4[i] = o;
  }
}

// ---------------- bias table: bias_all[h][64][64], mask folded in ----------------
__global__ void bias_kernel(const float* __restrict__ rpb, float* __restrict__ bias_all) {
  int h = blockIdx.x;
  for (int e = threadIdx.x; e < 4096; e += blockDim.x) {
    int n = e >> 6, m = e & 63;
    float v = -1e30f;
    if (n < 49 && m < 49) {
      int in_ = n / 7, jn = n % 7, im = m / 7, jm = m % 7;
      v = rpb[h * 169 + (im - in_ + 6) * 13 + (jm - jn + 6)];
    }
    bias_all[h * 4096 + e] = v;
  }
}

// ---------------- 256x256 8-phase GEMM: C[M,N] = A[M,K] @ B[N,K]^T + bias ----------------
// LDS per buffer (64KB): A[kk0] 0 / A[kk1] 16384 / B[kk0] 32768 / B[kk1] 49152.
// Buffer 1 at +65536. Panel layout [256 rows][32 f16]; 16B chunk swizzled by
// chunk_phys = chunk_log ^ ((row>>1)&3), applied on the GLOBAL source (write side)
// and on the ds_read address (read side) -- both reduce to lane constants.

#define VM4 asm volatile("s_waitcnt vmcnt(4)" ::: "memory")
#define VM0 asm volatile("s_waitcnt vmcnt(0)" ::: "memory")
#define NOVM ((void)0)
#define NOSTG ((void)0)

// one half-tile (16KB = 16 slots of 1KB): per wave 2 slots (wid*2, wid*2+1)
#define STAGE(GB, ROW0, COL0, LDSOFF)                                              \
  {                                                                                \
    const f16* s0_ = (GB) + (size_t)((ROW0) + wid * 32 + srow) * K + ((COL0) + sce); \
    __builtin_amdgcn_global_load_lds(G1P(s0_), L3P(lds + (LDSOFF) + wid * 2048), 16, 0, 0); \
    const f16* s1_ = s0_ + (size_t)16 * K;                                         \
    __builtin_amdgcn_global_load_lds(G1P(s1_), L3P(lds + (LDSOFF) + wid * 2048 + 1024), 16, 0, 0); \
  }

#define MFMA4(AREG, ROW)                                                           \
  acc[ROW][0] = __builtin_amdgcn_mfma_f32_16x16x32_f16(AREG, b0, acc[ROW][0], 0, 0, 0); \
  acc[ROW][1] = __builtin_amdgcn_mfma_f32_16x16x32_f16(AREG, b1, acc[ROW][1], 0, 0, 0); \
  acc[ROW][2] = __builtin_amdgcn_mfma_f32_16x16x32_f16(AREG, b2, acc[ROW][2], 0, 0, 0); \
  acc[ROW][3] = __builtin_amdgcn_mfma_f32_16x16x32_f16(AREG, b3, acc[ROW][3], 0, 0, 0);

#define PHASE(ABASE, BBASE, MH, STG, VMW)                                          \
  {                                                                                \
    f16x8 a0 = *(const f16x8*)((ABASE) + (wm * 128 + (MH) * 64 +  0 + l15) * 64 + swz); \
    f16x8 a1 = *(const f16x8*)((ABASE) + (wm * 128 + (MH) * 64 + 16 + l15) * 64 + swz); \
    f16x8 a2 = *(const f16x8*)((ABASE) + (wm * 128 + (MH) * 64 + 32 + l15) * 64 + swz); \
    f16x8 a3 = *(const f16x8*)((ABASE) + (wm * 128 + (MH) * 64 + 48 + l15) * 64 + swz); \
    if ((MH) == 0) {                                                               \
      b0 = *(const f16x8*)((BBASE) + (wn * 64 +  0 + l15) * 64 + swz);             \
      b1 = *(const f16x8*)((BBASE) + (wn * 64 + 16 + l15) * 64 + swz);             \
      b2 = *(const f16x8*)((BBASE) + (wn * 64 + 32 + l15) * 64 + swz);             \
      b3 = *(const f16x8*)((BBASE) + (wn * 64 + 48 + l15) * 64 + swz);             \
    }                                                                              \
    STG;                                                                           \
    __builtin_amdgcn_s_barrier();                                                  \
    asm volatile("s_waitcnt lgkmcnt(0)" ::: "memory");                             \
    __builtin_amdgcn_sched_barrier(0);                                             \
    __builtin_amdgcn_s_setprio(1);                                                 \
    MFMA4(a0, (MH) * 4 + 0) MFMA4(a1, (MH) * 4 + 1)                                \
    MFMA4(a2, (MH) * 4 + 2) MFMA4(a3, (MH) * 4 + 3)                                \
    __builtin_amdgcn_s_setprio(0);                                                 \
    VMW;                                                                           \
    __builtin_amdgcn_s_barrier();                                                  \
  }

template <typename OutT>
__global__ __launch_bounds__(512, 2)
void gemm256(const f16* __restrict__ A, const f16* __restrict__ B,
             const float* __restrict__ bias, OutT* __restrict__ C,
             int N, int K, int ntiles_n) {
  __shared__ char lds[131072];
  const int tid = threadIdx.x;
  const int wid = tid >> 6, ln = tid & 63;
  const int l15 = ln & 15, lhi = ln >> 4;
  const int wm = wid >> 2, wn = wid & 3;
  // lane constants: staging source chunk swizzle and fragment-read chunk swizzle
  const int srow = ln >> 2;                              // row within 16-row slot
  const int sce = (((ln & 3) ^ ((ln >> 3) & 3)) << 3);   // source element offset (swizzled)
  const int swz = ((lhi ^ ((l15 >> 1) & 3)) << 4);       // read byte-chunk offset (swizzled)

  // XCD-chunked 1D swizzle (grid divisible by 8), n-fastest for A-panel L2 reuse
  const int nblk = gridDim.x;
  const int wg = (blockIdx.x & 7) * (nblk >> 3) + (blockIdx.x >> 3);
  const int bn = wg % ntiles_n, bm = wg / ntiles_n;
  const int m0 = bm * 256, n0 = bn * 256;

  f32x4 acc[8][4];
#pragma unroll
  for (int i = 0; i < 8; ++i)
#pragma unroll
    for (int j = 0; j < 4; ++j) acc[i][j] = (f32x4){0.f, 0.f, 0.f, 0.f};
  f16x8 b0, b1, b2, b3;

  // prologue: tile0 (4 halves) + tile1 kk0 halves; keep last 2 halves in flight
  STAGE(A, m0, 0, 0);                 // Ak0(0) -> buf0
  STAGE(B, n0, 0, 32768);             // Bk0(0)
  STAGE(A, m0, 32, 16384);            // Ak1(0)
  STAGE(B, n0, 32, 49152);            // Bk1(0)
  STAGE(A, m0, 64, 65536);            // Ak0(1) -> buf1
  STAGE(B, n0, 64, 98304);            // Bk0(1)
  VM4;
  __builtin_amdgcn_s_barrier();

  // main: 7 iterations x 2 K-tiles (tiles 0..13); K = 1024 = 16 tiles of 64
  for (int i = 0; i < 7; ++i) {
    const int cT1k1 = (2 * i + 1) * 64 + 32;
    const int cT2k0 = (2 * i + 2) * 64;
    const int cT2k1 = cT2k0 + 32;
    const int cT3k0 = (2 * i + 3) * 64;
    // tile 2i (buf0)
    PHASE(lds + 0,      lds + 32768,  0, STAGE(A, m0, cT1k1, 81920),  NOVM);
    PHASE(lds + 0,      lds + 32768,  1, STAGE(B, n0, cT1k1, 114688), NOVM);
    PHASE(lds + 16384,  lds + 49152,  0, STAGE(A, m0, cT2k0, 0),      NOVM);
    PHASE(lds + 16384,  lds + 49152,  1, STAGE(B, n0, cT2k0, 32768),  VM4);
    // tile 2i+1 (buf1)
    PHASE(lds + 65536,  lds + 98304,  0, STAGE(A, m0, cT2k1, 16384),  NOVM);
    PHASE(lds + 65536,  lds + 98304,  1, STAGE(B, n0, cT2k1, 49152),  NOVM);
    PHASE(lds + 81920,  lds + 114688, 0, STAGE(A, m0, cT3k0, 65536),  NOVM);
    PHASE(lds + 81920,  lds + 114688, 1, STAGE(B, n0, cT3k0, 98304),  VM4);
  }
  // tail: tile 14 (buf0) -- stage only tile 15 kk1 halves, then drain
  PHASE(lds + 0,      lds + 32768,  0, STAGE(A, m0, 15 * 64 + 32, 81920),  NOVM);
  PHASE(lds + 0,      lds + 32768,  1, STAGE(B, n0, 15 * 64 + 32, 114688), NOVM);
  PHASE(lds + 16384,  lds + 49152,  0, NOSTG, NOVM);
  PHASE(lds + 16384,  lds + 49152,  1, NOSTG, VM0);
  // tile 15 (buf1)
  PHASE(lds + 65536,  lds + 98304,  0, NOSTG, NOVM);
  PHASE(lds + 65536,  lds + 98304,  1, NOSTG, NOVM);
  PHASE(lds + 81920,  lds + 114688, 0, NOSTG, NOVM);
  PHASE(lds + 81920,  lds + 114688, 1, NOSTG, NOVM);

  // epilogue
  float bv[4];
#pragma unroll
  for (int j = 0; j < 4; ++j) bv[j] = bias[n0 + wn * 64 + j * 16 + l15];
#pragma unroll
  for (int ii = 0; ii < 8; ++ii)
#pragma unroll
    for (int j = 0; j < 4; ++j)
#pragma unroll
      for (int r = 0; r < 4; ++r) {
        int gr = m0 + wm * 128 + ii * 16 + lhi * 4 + r;
        int gc = n0 + wn * 64 + j * 16 + l15;
        C[(size_t)gr * N + gc] = (OutT)(acc[ii][j][r] + bv[j]);
      }
}

// ---------------- attention: one wave per (window, head) ----------------
__global__ __launch_bounds__(64)
void attn_kernel(const f16* __restrict__ qkv,        // [MTOT][3072] q|k|v
                 const float* __restrict__ bias_all, // [16][64][64]
                 f16* __restrict__ out) {             // [MTOT][1024]
  __shared__ char lds[24576];  // K:[0,8K)  Vt:[8K,16K)  P:[16K,24K)
  const int bh = blockIdx.x;
  const int b = bh >> 4, h = bh & 15;
  const int ln = threadIdx.x;
  const int l15 = ln & 15, lhi = ln >> 4;
  const size_t base = (size_t)b * 49;

  f16x8 qf[4][2];
#pragma unroll
  for (int t = 0; t < 4; ++t) {
    size_t row = base + t * 16 + l15;
    if (row > MROW_MAX) row = MROW_MAX;
    const f16* qp = qkv + row * 3072 + h * 64 + lhi * 8;
    qf[t][0] = *(const f16x8*)(qp);
    qf[t][1] = *(const f16x8*)(qp + 32);
  }
  {
    int rA = ln >> 3, lc = ln & 7;
#pragma unroll
    for (int c = 0; c < 8; ++c) {
      int r = c * 8 + rA;
      int ce = (lc ^ (r & 7)) << 3;
      size_t row = base + r;
      if (row > MROW_MAX) row = MROW_MAX;
      const f16* g = qkv + row * 3072 + 1024 + h * 64 + ce;
      __builtin_amdgcn_global_load_lds(G1P(g), L3P(lds + c * 1024), 16, 0, 0);
    }
  }
  {
    size_t row = base + ln;
    if (row > MROW_MAX) row = MROW_MAX;
    const f16* vp = qkv + row * 3072 + 2048 + h * 64;
    f16x8 vr[8];
#pragma unroll
    for (int j = 0; j < 8; ++j) vr[j] = *(const f16x8*)(vp + j * 8);
#pragma unroll
    for (int d = 0; d < 64; ++d)
      *(f16*)(lds + 8192 + d * 128 + ((ln * 2) ^ ((d & 7) << 4))) = vr[d >> 3][d & 7];
  }
  __syncthreads();

  f32x4 acc[4][4];
#pragma unroll
  for (int i = 0; i < 4; ++i)
#pragma unroll
    for (int j = 0; j < 4; ++j) acc[i][j] = (f32x4){0.f, 0.f, 0.f, 0.f};
#pragma unroll
  for (int kk = 0; kk < 2; ++kk) {
    f16x8 bf[4];
#pragma unroll
    for (int t = 0; t < 4; ++t) {
      int mr = t * 16 + l15;
      int pb = (kk * 64 + lhi * 16) ^ ((mr & 7) << 4);
      bf[t] = *(const f16x8*)(lds + mr * 128 + pb);
    }
#pragma unroll
    for (int i = 0; i < 4; ++i)
#pragma unroll
      for (int j = 0; j < 4; ++j)
        acc[i][j] = __builtin_amdgcn_mfma_f32_16x16x32_f16(qf[i][kk], bf[j], acc[i][j], 0, 0, 0);
  }

  const float* bb = bias_all + h * 4096;
#pragma unroll
  for (int i = 0; i < 4; ++i) {
#pragma unroll
    for (int r = 0; r < 4; ++r) {
      int n = i * 16 + lhi * 4 + r;
      float lv[4];
#pragma unroll
      for (int j = 0; j < 4; ++j)
        lv[j] = acc[i][j][r] * 0.125f + bb[n * 64 + j * 16 + l15];
      float Mx = fmaxf(fmaxf(lv[0], lv[1]), fmaxf(lv[2], lv[3]));
#pragma unroll
      for (int off = 1; off < 16; off <<= 1) Mx = fmaxf(Mx, __shfl_xor(Mx, off));
      float s = 0.f;
#pragma unroll
      for (int j = 0; j < 4; ++j) { lv[j] = __expf(lv[j] - Mx); s += lv[j]; }
#pragma unroll
      for (int off = 1; off < 16; off <<= 1) s += __shfl_xor(s, off);
      float inv = 1.f / s;
#pragma unroll
      for (int j = 0; j < 4; ++j) {
        int m = j * 16 + l15;
        *(f16*)(lds + 16384 + n * 128 + ((m * 2) ^ ((n & 7) << 4))) = (f16)(lv[j] * inv);
      }
    }
  }
  __syncthreads();

  f32x4 o[4][4];
#pragma unroll
  for (int i = 0; i < 4; ++i)
#pragma unroll
    for (int j = 0; j < 4; ++j) o[i][j] = (f32x4){0.f, 0.f, 0.f, 0.f};
#pragma unroll
  for (int kk = 0; kk < 2; ++kk) {
    f16x8 af[4], bf[4];
#pragma unroll
    for (int t = 0; t < 4; ++t) {
      int nr = t * 16 + l15;
      int pb = (kk * 64 + lhi * 16) ^ ((nr & 7) << 4);
      af[t] = *(const f16x8*)(lds + 16384 + nr * 128 + pb);
      bf[t] = *(const f16x8*)(lds + 8192 + nr * 128 + pb);
    }
#pragma unroll
    for (int i = 0; i < 4; ++i)
#pragma unroll
      for (int j = 0; j < 4; ++j)
        o[i][j] = __builtin_amdgcn_mfma_f32_16x16x32_f16(af[i], bf[j], o[i][j], 0, 0, 0);
  }
#pragma unroll
  for (int i = 0; i < 4; ++i)
#pragma unroll
    for (int j = 0; j < 4; ++j)
#pragma unroll
      for (int r = 0; r < 4; ++r) {
        int n = i * 16 + lhi * 4 + r;
        if (n < 49)
          out[(base + n) * 1024 + h * 64 + j * 16 + l15] = (f16)o[i][j][r];
      }
}

extern "C" void kernel_launch(void* const* d_in, const int* in_sizes, int n_in,
                              void* d_out, int out_size, void* d_ws, size_t ws_size,
                              hipStream_t stream) {
  const float* x      = (const float*)d_in[0];  // [100352][1024]
  const float* qkv_w  = (const float*)d_in[1];  // [3072][1024]
  const float* qkv_b  = (const float*)d_in[2];  // [3072]
  const float* rpb    = (const float*)d_in[3];  // [16][13][13]
  const float* proj_w = (const float*)d_in[4];  // [1024][1024]
  const float* proj_b = (const float*)d_in[5];  // [1024]
  float* out = (float*)d_out;

  char* ws = (char*)d_ws;
  f16*   x16      = (f16*)(ws);                              // 205,520,896
  f16*   wq16     = (f16*)(ws + 205520896);                  //   6,291,456
  f16*   wp16     = (f16*)(ws + 211812352);                  //   2,097,152
  f16*   qkv16    = (f16*)(ws + 213909504);                  // 616,562,688
  f16*   attn16   = (f16*)(ws + 830472192);                  // 205,520,896
  float* bias_all = (float*)(ws + 1035993088);               //     262,144

  cvt_kernel<<<2048, 256, 0, stream>>>(x, x16, 102760448 / 4);
  cvt_kernel<<<1024, 256, 0, stream>>>(qkv_w, wq16, 3145728 / 4);
  cvt_kernel<<<512, 256, 0, stream>>>(proj_w, wp16, 1048576 / 4);
  bias_kernel<<<16, 64, 0, stream>>>(rpb, bias_all);

  // qkv = x @ qkv_w^T + qkv_b   [100352][3072] fp16   (392 x 12 tiles)
  gemm256<f16><<<4704, 512, 0, stream>>>(x16, wq16, qkv_b, qkv16, 3072, 1024, 12);
  // attention per (window, head)
  attn_kernel<<<2048 * 16, 64, 0, stream>>>(qkv16, bias_all, attn16);
  // out = attn @ proj_w^T + proj_b   [100352][1024] fp32  (392 x 4 tiles)
  gemm256<float><<<1568, 512, 0, stream>>>(attn16, wp16, proj_b, out, 1024, 1024, 4);
}